// Round 11
// baseline (40.990 us; speedup 1.0000x reference)
//
#include <hip/hip_runtime.h>
#include <math.h>

#define TS 49
#define LOG49 3.8918202981106265f
#define LN2 0.6931471805599453f

typedef short bf16x8 __attribute__((ext_vector_type(8)));   // 8 bf16 = 4 VGPRs
typedef float f32x4 __attribute__((ext_vector_type(4)));
typedef float f32x4u __attribute__((ext_vector_type(4), aligned(4)));
typedef float f32x16 __attribute__((ext_vector_type(16)));  // 32x32 MFMA C/D
typedef unsigned u32x4 __attribute__((ext_vector_type(4)));

// State relabeling: position p holds original state (p+1)%49 -> emission col = p.
// ws layout: bytes [0,8192): E A-fragments bf16[n=2][m=4][lane=64][s=8]
//   jp = 32n + (lane&31), kp = 16m + 8*(lane>>5) + s
//   value = exp(trans[(jp+1)%49][(kp+1)%49] - Tmax), zero if jp>=49 || kp>=49.
// byte 8192: float Tmax.

__global__ void prep_kernel(const float* __restrict__ tf, const float* __restrict__ w2,
                            const float* __restrict__ b2, float* __restrict__ ws) {
    __shared__ float tr[TS * TS];
    __shared__ float red[256];
    const int tid = threadIdx.x;
    const float w0 = w2[0], w1 = w2[1], w2v = w2[2], w3 = w2[3], w4 = w2[4], w5 = w2[5];
    const float bb = b2[0];
    float lmax = -INFINITY;
    for (int idx = tid; idx < TS * TS; idx += 256) {
        const float* p = tf + idx * 6;
        float s = bb + p[0]*w0 + p[1]*w1 + p[2]*w2v + p[3]*w3 + p[4]*w4 + p[5]*w5;
        tr[idx] = s;
        lmax = fmaxf(lmax, s);
    }
    red[tid] = lmax;
    __syncthreads();
    for (int s = 128; s > 0; s >>= 1) {
        if (tid < s) red[tid] = fmaxf(red[tid], red[tid + s]);
        __syncthreads();
    }
    const float Tmax = red[0];
    __syncthreads();
    unsigned short* B = (unsigned short*)ws;
    for (int idx = tid; idx < 4096; idx += 256) {
        const int s = idx & 7;
        const int l = (idx >> 3) & 63;
        const int m = (idx >> 9) & 3;
        const int n = idx >> 11;
        const int jp = 32 * n + (l & 31);
        const int kp = 16 * m + 8 * (l >> 5) + s;
        float v = 0.0f;
        if (jp < TS && kp < TS) {
            const int jj = (jp + 1) % TS, kk = (kp + 1) % TS;
            v = __expf(tr[jj * TS + kk] - Tmax);
        }
        unsigned bts = __float_as_uint(v);
        B[idx] = (unsigned short)((bts + 0x7FFFu + ((bts >> 16) & 1u)) >> 16);  // rne bf16
    }
    if (tid == 0) ((float*)ws)[2048] = Tmax;
}

__device__ __forceinline__ unsigned cvtpk_bf16(float lo, float hi) {
    unsigned d;  // D[15:0]=bf16(lo), D[31:16]=bf16(hi)
    asm("v_cvt_pk_bf16_f32 %0, %1, %2" : "=v"(d) : "v"(lo), "v"(hi));
    return d;
}

// One wave = 32 chains (chain = lane&31). v[n] f32x16: tile n covers positions
// 32n + 8*(r>>2) + 4*(lane>>5) + (r&3). B-frags via cvt_pk + permlane32_swap.
// Pipeline: ee for step I+1 computed during step I (exp off critical path);
// loads issued 4 steps ahead; MFMA accumulation split 2+2 with vadd merge.
__global__ __launch_bounds__(64, 1) void crf_fwd(const float* __restrict__ emis,
                                                 const unsigned short* __restrict__ wsE,
                                                 float* __restrict__ out, int L) {
    const int l = threadIdx.x;
    const int h = l >> 5;    // lane half
    const int ch = l & 31;   // chain index within block
    const int b0 = blockIdx.x * 32;
    const float Tmax = ((const float*)wsE)[2048];

    // E A-fragments, register-resident
    bf16x8 E[2][4];
    {
        const bf16x8* Et = (const bf16x8*)wsE;
        #pragma unroll
        for (int n = 0; n < 2; ++n)
            #pragma unroll
            for (int m = 0; m < 4; ++m) E[n][m] = Et[(n * 4 + m) * 64 + l];
    }

    const int LT = L * TS;
    const float* eb  = emis + (size_t)(b0 + ch) * LT + 4 * h;  // vector cols 8j+4h
    const float* ebs = emis + (size_t)(b0 + ch) * LT + 48;     // scalar col 48

    f32x4 pfv[4][6];  // [slot][j]; static indexing only
    float pfs[4];

#define LQ(STEP, SLOT) do {                                                           \
    const int _o = (STEP) * TS;                                                       \
    _Pragma("unroll")                                                                 \
    for (int j = 0; j < 6; ++j)                                                       \
        pfv[SLOT][j] = *(const f32x4u*)(eb + _o + 8 * j);                             \
    pfs[SLOT] = ebs[_o];                                                              \
} while (0)

    f32x16 acc[2];        // E @ V_{I-1}
    f32x16 v[2];          // V_I
    f32x16 ee0[2], ee1[2];// exp(emissions), ping-pong (computed 1 step early)
    float fac = 1.f, pend = 0.f, sc = 0.f;

    // exp of slot emissions -> DST layout matching v (dead entries = 1.0; acc=0 there)
#define EXPSEL(DST, SLOT) do {                                                        \
    _Pragma("unroll")                                                                 \
    for (int q = 0; q < 4; ++q)                                                       \
        _Pragma("unroll")                                                             \
        for (int e = 0; e < 4; ++e) {                                                 \
            const int r = 4 * q + e;                                                  \
            DST[0][r] = __expf(pfv[SLOT][q][e]);                                      \
            float t1;                                                                 \
            if (q < 2)       t1 = __expf(pfv[SLOT][4 + q][e]);                        \
            else if (q == 2) t1 = (h == 0 && e == 0) ? __expf(pfs[SLOT]) : 1.0f;      \
            else             t1 = 1.0f;                                               \
            DST[1][r] = t1;                                                           \
        }                                                                             \
} while (0)

#define MULT(EC, DO_A) do {                                                           \
    _Pragma("unroll")                                                                 \
    for (int n = 0; n < 2; ++n)                                                       \
        _Pragma("unroll")                                                             \
        for (int r = 0; r < 16; ++r) {                                                \
            float m_ = acc[n][r] * EC[n][r];                                          \
            if (DO_A) m_ *= fac;                                                      \
            v[n][r] = m_;                                                             \
        }                                                                             \
} while (0)

    // pack v -> B-frags, then split-accumulate MFMAs (2 serial + 2 serial, vadd merge)
#define PACKMM() do {                                                                 \
    u32x4 Bu[4];                                                                      \
    _Pragma("unroll")                                                                 \
    for (int n = 0; n < 2; ++n) {                                                     \
        unsigned w0 = cvtpk_bf16(v[n][0],  v[n][1]);                                  \
        unsigned w1 = cvtpk_bf16(v[n][2],  v[n][3]);                                  \
        unsigned w2 = cvtpk_bf16(v[n][4],  v[n][5]);                                  \
        unsigned w3 = cvtpk_bf16(v[n][6],  v[n][7]);                                  \
        unsigned w4 = cvtpk_bf16(v[n][8],  v[n][9]);                                  \
        unsigned w5 = cvtpk_bf16(v[n][10], v[n][11]);                                 \
        unsigned w6 = cvtpk_bf16(v[n][12], v[n][13]);                                 \
        unsigned w7 = cvtpk_bf16(v[n][14], v[n][15]);                                 \
        asm("v_permlane32_swap_b32 %0, %1" : "+v"(w0), "+v"(w2));                     \
        asm("v_permlane32_swap_b32 %0, %1" : "+v"(w1), "+v"(w3));                     \
        asm("v_permlane32_swap_b32 %0, %1" : "+v"(w4), "+v"(w6));                     \
        asm("v_permlane32_swap_b32 %0, %1" : "+v"(w5), "+v"(w7));                     \
        Bu[2 * n]     = (u32x4){w0, w1, w2, w3};                                      \
        Bu[2 * n + 1] = (u32x4){w4, w5, w6, w7};                                      \
    }                                                                                 \
    const f32x16 z_ = {0.f,0.f,0.f,0.f,0.f,0.f,0.f,0.f,                              \
                       0.f,0.f,0.f,0.f,0.f,0.f,0.f,0.f};                             \
    _Pragma("unroll")                                                                 \
    for (int n = 0; n < 2; ++n) {                                                     \
        f32x16 p_ = __builtin_amdgcn_mfma_f32_32x32x16_bf16(                          \
                        E[n][0], __builtin_bit_cast(bf16x8, Bu[0]), z_, 0, 0, 0);     \
        p_ = __builtin_amdgcn_mfma_f32_32x32x16_bf16(                                 \
                        E[n][1], __builtin_bit_cast(bf16x8, Bu[1]), p_, 0, 0, 0);     \
        f32x16 q_ = __builtin_amdgcn_mfma_f32_32x32x16_bf16(                          \
                        E[n][2], __builtin_bit_cast(bf16x8, Bu[2]), z_, 0, 0, 0);     \
        q_ = __builtin_amdgcn_mfma_f32_32x32x16_bf16(                                 \
                        E[n][3], __builtin_bit_cast(bf16x8, Bu[3]), q_, 0, 0, 0);     \
        acc[n] = p_ + q_;                                                             \
    }                                                                                 \
} while (0)

#define RENC() do {                                                                   \
    float mx = v[0][0];                                                               \
    _Pragma("unroll")                                                                 \
    for (int r = 1; r < 16; ++r) mx = fmaxf(mx, v[0][r]);                             \
    _Pragma("unroll")                                                                 \
    for (int r = 0; r < 16; ++r) mx = fmaxf(mx, v[1][r]);                             \
    mx = fmaxf(mx, __shfl_xor(mx, 32, 64));                                           \
    const unsigned ex = __float_as_uint(mx) >> 23;                                    \
    fac  = __uint_as_float((254u - ex) << 23);                                        \
    pend = (float)((int)ex - 127) * LN2;                                              \
} while (0)

#define STEP(I, EC, EN, SN, LSLOT, DO_C, DO_A) do {                                   \
    if ((I) + 4 < L) LQ((I) + 4, LSLOT);   /* LSLOT = I%4 (freed by EXPSEL at I-1) */ \
    EXPSEL(EN, SN);                        /* ee for step I+1; 3 steps of vmcnt slack */ \
    asm volatile("" ::: "memory");         /* confine loads to their iteration */     \
    MULT(EC, DO_A);                                                                   \
    if (DO_A) sc += pend;                                                             \
    PACKMM();                                                                         \
    if (DO_C) RENC();                                                                 \
} while (0)

    // prologue: slots 0..3 = steps 0..3
    LQ(0, 0);
    if (L > 1) LQ(1, 1);
    if (L > 2) LQ(2, 2);
    if (L > 3) LQ(3, 3);
    asm volatile("" ::: "memory");

    // init V_0 = exp(emit[0][pos]) with dead positions = 0 (consumes slot 0)
    #pragma unroll
    for (int q = 0; q < 4; ++q)
        #pragma unroll
        for (int e = 0; e < 4; ++e) {
            const int r = 4 * q + e;
            v[0][r] = __expf(pfv[0][q][e]);
            float val;
            if (q < 2)       val = __expf(pfv[0][4 + q][e]);
            else if (q == 2) val = (h == 0 && e == 0) ? __expf(pfs[0]) : 0.0f;
            else             val = 0.0f;
            v[1][r] = val;
        }
    if (L > 4) LQ(4, 0);        // slot 0 now free
    EXPSEL(ee1, 1);             // ee for step 1
    asm volatile("" ::: "memory");
    PACKMM();                   // acc = E @ V_0

    const int S = L - 1;  // steps 1..S
    int i = 1;
    for (; i + 3 <= S; i += 4) {  // i == 1 mod 4 -> static slots
        STEP(i + 0, ee1, ee0, 2, 1, 1, 0);
        STEP(i + 1, ee0, ee1, 3, 2, 0, 1);
        STEP(i + 2, ee1, ee0, 0, 3, 0, 0);
        STEP(i + 3, ee0, ee1, 1, 0, 0, 0);
    }
    if (i <= S)     STEP(i,     ee1, ee0, 2, 1, 1, 0);
    if (i + 1 <= S) STEP(i + 1, ee0, ee1, 3, 2, 0, 1);
    if (i + 2 <= S) STEP(i + 2, ee1, ee0, 0, 3, 0, 0);
#undef STEP
#undef RENC
#undef PACKMM
#undef MULT
#undef EXPSEL
#undef LQ

    // final: alpha[chain] = sc + log(sum_pos V) + LOG49 + (L-1)*Tmax
    float s = 0.0f;
    #pragma unroll
    for (int r = 0; r < 16; ++r) s += v[0][r];
    #pragma unroll
    for (int r = 0; r < 16; ++r) s += v[1][r];
    s += __shfl_xor(s, 32, 64);
    const float res = sc + __logf(s) + LOG49 + (float)(L - 1) * Tmax;
    if (l < 32) out[b0 + ch] = res;
}

extern "C" void kernel_launch(void* const* d_in, const int* in_sizes, int n_in,
                              void* d_out, int out_size, void* d_ws, size_t ws_size,
                              hipStream_t stream) {
    const float* emis = (const float*)d_in[0];
    const float* tf   = (const float*)d_in[1];
    const float* w2   = (const float*)d_in[2];
    const float* b2   = (const float*)d_in[3];
    float* out = (float*)d_out;
    float* ws  = (float*)d_ws;

    const int B = out_size;                // 8192
    const int L = in_sizes[0] / (B * TS);  // 48

    prep_kernel<<<1, 256, 0, stream>>>(tf, w2, b2, ws);
    crf_fwd<<<B / 32, 64, 0, stream>>>(emis, (const unsigned short*)ws, out, L);
}

// Round 12
// 29.212 us; speedup vs baseline: 1.4032x; 1.4032x over previous
//
#include <hip/hip_runtime.h>
#include <math.h>

#define TS 49
#define LOG49 3.8918202981106265f
#define LN2 0.6931471805599453f

typedef short bf16x8 __attribute__((ext_vector_type(8)));  // 8 bf16 = 4 VGPRs
typedef float f32x4 __attribute__((ext_vector_type(4)));
typedef float f32x4u __attribute__((ext_vector_type(4), aligned(4)));

// State relabeling: position p holds original state (p+1)%49 -> emission col = p.
// ws layout (identical to R8):
//   bytes [0, 8192): B-fragments bf16[nt=4][h=2][lane=64][s=8]
//     value = exp(trans[(jp+1)%49][(kp+1)%49] - Tmax), jp = 4*(lane&15)+nt (out pos),
//     kp = 32*h + 8*(lane>>4) + s (in pos); zero outside jp<49 && kp<49.
//   byte 8192: float Tmax

__global__ void prep_kernel(const float* __restrict__ tf, const float* __restrict__ w2,
                            const float* __restrict__ b2, float* __restrict__ ws) {
    __shared__ float tr[TS * TS];
    __shared__ float red[256];
    const int tid = threadIdx.x;
    const float w0 = w2[0], w1 = w2[1], w2v = w2[2], w3 = w2[3], w4 = w2[4], w5 = w2[5];
    const float bb = b2[0];
    float lmax = -INFINITY;
    for (int idx = tid; idx < TS * TS; idx += 256) {
        const float* p = tf + idx * 6;
        float s = bb + p[0]*w0 + p[1]*w1 + p[2]*w2v + p[3]*w3 + p[4]*w4 + p[5]*w5;
        tr[idx] = s;
        lmax = fmaxf(lmax, s);
    }
    red[tid] = lmax;
    __syncthreads();
    for (int s = 128; s > 0; s >>= 1) {
        if (tid < s) red[tid] = fmaxf(red[tid], red[tid + s]);
        __syncthreads();
    }
    const float Tmax = red[0];
    __syncthreads();
    unsigned short* B = (unsigned short*)ws;
    for (int idx = tid; idx < 4096; idx += 256) {
        const int s  = idx & 7;
        const int l  = (idx >> 3) & 63;
        const int h  = (idx >> 9) & 1;
        const int nt = idx >> 10;
        const int jp = 4 * (l & 15) + nt;
        const int kp = 32 * h + 8 * (l >> 4) + s;
        float v = 0.0f;
        if (jp < TS && kp < TS) {
            const int jj = (jp + 1) % TS, kk = (kp + 1) % TS;
            v = __expf(tr[jj * TS + kk] - Tmax);
        }
        unsigned bts = __float_as_uint(v);
        B[idx] = (unsigned short)((bts + 0x7FFFu + ((bts >> 16) & 1u)) >> 16);  // rne bf16
    }
    if (tid == 0) ((float*)ws)[2048] = Tmax;  // byte 8192
}

__device__ __forceinline__ unsigned cvtpk_bf16(float lo, float hi) {
    unsigned d;  // D[15:0]=bf16(lo), D[31:16]=bf16(hi)
    asm("v_cvt_pk_bf16_f32 %0, %1, %2" : "=v"(d) : "v"(lo), "v"(hi));
    return d;
}

// One wave = 8 chains (t=0..1): internal V-row = 4*(l>>4)+t, global chain = b0+2g+t.
// Internal rows 4g+2, 4g+3 are dead (zeroed once). Position p = 4*(l&15)+nt.
// V16: chain-major [16][64 bf16], XOR-swizzled (R8-validated, 0 bank conflicts).
__global__ __launch_bounds__(64, 2) void crf_fwd(const float* __restrict__ emis,
                                                 const unsigned short* __restrict__ wsB,
                                                 float* __restrict__ out, int L) {
    __shared__ __align__(16) unsigned short V16[1024];
    const int l = threadIdx.x, g = l >> 4, c0 = l & 15;
    const int b0 = blockIdx.x * 8;
    const float Tmax = ((const float*)wsB)[2048];

    // E fragments (B-operand), register-resident
    bf16x8 Bf[4][2];
    {
        const bf16x8* Bt = (const bf16x8*)wsB;
        #pragma unroll
        for (int nt = 0; nt < 4; ++nt)
            #pragma unroll
            for (int h = 0; h < 2; ++h) Bf[nt][h] = Bt[(nt * 2 + h) * 64 + l];
    }

    // V16 LDS indices (R8-validated swizzle)
    int wi[4];
    #pragma unroll
    for (int t = 0; t < 4; ++t) {
        const int ch = 4 * g + t;
        wi[t] = ch * 16 + (c0 ^ ((ch & 7) << 1));  // uint2 units
    }
    const int ra0 = c0 * 8 + (g ^ (c0 & 7));        // bf16x8 units, k 0..31
    const int ra1 = c0 * 8 + ((4 + g) ^ (c0 & 7));  // k 32..63
    uint2* const Vw = (uint2*)V16;
    const bf16x8* const Vr = (const bf16x8*)V16;

    // zero dead internal rows (t=2,3) once: their A-garbage would otherwise be stale
    {
        const uint2 z = {0u, 0u};
        Vw[wi[2]] = z;
        Vw[wi[3]] = z;
    }

    // Emission addressing: positions 4c0..4c0+3 (aligned x4); edge lanes clamp to 45.
    const int LT = L * TS;
    const bool sel12 = (c0 >= 12);
    const int col4 = sel12 ? 45 : 4 * c0;
    const float* ebase[2];
    #pragma unroll
    for (int t = 0; t < 2; ++t)
        ebase[t] = emis + (size_t)(b0 + 2 * g + t) * LT + col4;

    f32x4 pf[4][2];  // [slot][t], statically indexed only

#define LQ(STEP, SLOT) do {                                                           \
    _Pragma("unroll")                                                                 \
    for (int t = 0; t < 2; ++t)                                                       \
        pf[SLOT][t] = *(const f32x4u*)(ebase[t] + (STEP) * TS);                       \
} while (0)

#define EESEL(DST, SLOT) do {                                                         \
    _Pragma("unroll")                                                                 \
    for (int t = 0; t < 2; ++t) {                                                     \
        const f32x4 q = pf[SLOT][t];                                                  \
        DST[0][t] = __expf(sel12 ? q.w : q.x);                                        \
        DST[1][t] = __expf(q.y);                                                      \
        DST[2][t] = __expf(q.z);                                                      \
        DST[3][t] = __expf(q.w);                                                      \
    }                                                                                 \
} while (0)

    // prologue: fill 4 slots
    LQ(0, 0);
    if (L > 1) LQ(1, 1);
    if (L > 2) LQ(2, 2);
    if (L > 3) LQ(3, 3);

    // init V_0 from slot 0: v = exp(emit[0][p]), dead positions -> 0
    float v[4][2];
    #pragma unroll
    for (int t = 0; t < 2; ++t) {
        const f32x4 q = pf[0][t];
        const float i0 = sel12 ? q.w : q.x;
        v[0][t] = (4 * c0 + 0 < TS) ? __expf(i0)  : 0.0f;
        v[1][t] = (4 * c0 + 1 < TS) ? __expf(q.y) : 0.0f;
        v[2][t] = (4 * c0 + 2 < TS) ? __expf(q.z) : 0.0f;
        v[3][t] = (4 * c0 + 3 < TS) ? __expf(q.w) : 0.0f;
    }

    float ee0[4][2], ee1[4][2];
    EESEL(ee1, 1);  // emissions for step 1

    float sc[2]   = {0.f, 0.f};
    float fac[2]  = {1.f, 1.f};
    float pend[2] = {0.f, 0.f};

#define STEP(I, EC, EN, SN, SL, DO_C, DO_A) do {                                      \
    /* 1: pack v -> bf16, 2 x ds_write_b64 (swizzled); rows 4g+t, t<2 */              \
    _Pragma("unroll")                                                                 \
    for (int t = 0; t < 2; ++t) {                                                     \
        uint2 u;                                                                      \
        u.x = cvtpk_bf16(v[0][t], v[1][t]);                                           \
        u.y = cvtpk_bf16(v[2][t], v[3][t]);                                           \
        Vw[wi[t]] = u;                                                                \
    }                                                                                 \
    /* 2: next step's ee (pads DS drain; loads landed >=3 steps ago) */               \
    EESEL(EN, SN);                                                                    \
    /* 3: issue loads for step I+3 into the freed slot */                             \
    if ((I) + 3 < L) LQ((I) + 3, SL);                                                 \
    asm volatile("" ::: "memory");                                                    \
    /* 4: A-fragments (conflict-free b128; same-wave DS in-order) */                  \
    const bf16x8 A0 = Vr[ra0];                                                        \
    const bf16x8 A1 = Vr[ra1];                                                        \
    /* 5+6: MFMA + emission/renorm multiply (C rows t<2 live) */                      \
    _Pragma("unroll")                                                                 \
    for (int nt = 0; nt < 4; ++nt) {                                                  \
        f32x4 acc = {0.f, 0.f, 0.f, 0.f};                                             \
        acc = __builtin_amdgcn_mfma_f32_16x16x32_bf16(A0, Bf[nt][0], acc, 0, 0, 0);   \
        acc = __builtin_amdgcn_mfma_f32_16x16x32_bf16(A1, Bf[nt][1], acc, 0, 0, 0);   \
        _Pragma("unroll")                                                             \
        for (int t = 0; t < 2; ++t) {                                                 \
            float nv = acc[t] * EC[nt][t];                                            \
            if (DO_A) nv *= fac[t];                                                   \
            v[nt][t] = nv;                                                            \
        }                                                                             \
    }                                                                                 \
    if (DO_A) {                                                                       \
        _Pragma("unroll")                                                             \
        for (int t = 0; t < 2; ++t) sc[t] += pend[t];                                 \
    }                                                                                 \
    /* 7: renorm factor (applied next step; off critical path) */                     \
    if (DO_C) {                                                                       \
        _Pragma("unroll")                                                             \
        for (int t = 0; t < 2; ++t) {                                                 \
            float mx = fmaxf(fmaxf(v[0][t], v[1][t]), fmaxf(v[2][t], v[3][t]));       \
            mx = fmaxf(mx, __shfl_xor(mx, 1, 64));                                    \
            mx = fmaxf(mx, __shfl_xor(mx, 2, 64));                                    \
            mx = fmaxf(mx, __shfl_xor(mx, 4, 64));                                    \
            mx = fmaxf(mx, __shfl_xor(mx, 8, 64));                                    \
            const unsigned ex = __float_as_uint(mx) >> 23;                            \
            fac[t]  = __uint_as_float((254u - ex) << 23);                             \
            pend[t] = (float)((int)ex - 127) * LN2;                                   \
        }                                                                             \
    }                                                                                 \
} while (0)

    const int S = L - 1;  // steps 1..S
    int i = 1;
    for (; i + 3 <= S; i += 4) {  // i == 1 mod 4 -> static pf slots
        STEP(i + 0, ee1, ee0, 2, 0, 1, 0);
        STEP(i + 1, ee0, ee1, 3, 1, 0, 1);
        STEP(i + 2, ee1, ee0, 0, 2, 0, 0);
        STEP(i + 3, ee0, ee1, 1, 3, 0, 0);
    }
    if (i <= S)     STEP(i,     ee1, ee0, 2, 0, 1, 0);
    if (i + 1 <= S) STEP(i + 1, ee0, ee1, 3, 1, 0, 1);
    if (i + 2 <= S) STEP(i + 2, ee1, ee0, 0, 2, 0, 0);
#undef STEP
#undef EESEL
#undef LQ

    // final: alpha[chain] = sc + log(sum_p V) + LOG49 + (L-1)*Tmax
    float res[2];
    #pragma unroll
    for (int t = 0; t < 2; ++t) {
        float s = (v[0][t] + v[1][t]) + (v[2][t] + v[3][t]);
        s += __shfl_xor(s, 1, 64);
        s += __shfl_xor(s, 2, 64);
        s += __shfl_xor(s, 4, 64);
        s += __shfl_xor(s, 8, 64);
        res[t] = sc[t] + __logf(s) + LOG49 + (float)(L - 1) * Tmax;
    }
    if (c0 == 0) {
        #pragma unroll
        for (int t = 0; t < 2; ++t) out[b0 + 2 * g + t] = res[t];
    }
}

extern "C" void kernel_launch(void* const* d_in, const int* in_sizes, int n_in,
                              void* d_out, int out_size, void* d_ws, size_t ws_size,
                              hipStream_t stream) {
    const float* emis = (const float*)d_in[0];
    const float* tf   = (const float*)d_in[1];
    const float* w2   = (const float*)d_in[2];
    const float* b2   = (const float*)d_in[3];
    float* out = (float*)d_out;
    float* ws  = (float*)d_ws;

    const int B = out_size;                // 8192
    const int L = in_sizes[0] / (B * TS);  // 48

    prep_kernel<<<1, 256, 0, stream>>>(tf, w2, b2, ws);
    crf_fwd<<<B / 8, 64, 0, stream>>>(emis, (const unsigned short*)ws, out, L);
}

// Round 13
// 28.596 us; speedup vs baseline: 1.4334x; 1.0215x over previous
//
#include <hip/hip_runtime.h>
#include <math.h>

#define TS 49
#define LOG49 3.8918202981106265f
#define LN2 0.6931471805599453f

typedef short bf16x8 __attribute__((ext_vector_type(8)));  // 8 bf16 = 4 VGPRs
typedef float f32x4 __attribute__((ext_vector_type(4)));
typedef float f32x4u __attribute__((ext_vector_type(4), aligned(4)));

// State relabeling: position p holds original state (p+1)%49 -> emission col = p.
// ws layout (identical to R8/R12):
//   bytes [0, 8192): B-fragments bf16[nt=4][h=2][lane=64][s=8]
//     value = exp(trans[(jp+1)%49][(kp+1)%49] - Tmax), jp = 4*(lane&15)+nt (out pos),
//     kp = 32*h + 8*(lane>>4) + s (in pos); zero outside jp<49 && kp<49.
//   byte 8192: float Tmax

__global__ void prep_kernel(const float* __restrict__ tf, const float* __restrict__ w2,
                            const float* __restrict__ b2, float* __restrict__ ws) {
    __shared__ float tr[TS * TS];
    __shared__ float red[256];
    const int tid = threadIdx.x;
    const float w0 = w2[0], w1 = w2[1], w2v = w2[2], w3 = w2[3], w4 = w2[4], w5 = w2[5];
    const float bb = b2[0];
    float lmax = -INFINITY;
    for (int idx = tid; idx < TS * TS; idx += 256) {
        const float* p = tf + idx * 6;
        float s = bb + p[0]*w0 + p[1]*w1 + p[2]*w2v + p[3]*w3 + p[4]*w4 + p[5]*w5;
        tr[idx] = s;
        lmax = fmaxf(lmax, s);
    }
    red[tid] = lmax;
    __syncthreads();
    for (int s = 128; s > 0; s >>= 1) {
        if (tid < s) red[tid] = fmaxf(red[tid], red[tid + s]);
        __syncthreads();
    }
    const float Tmax = red[0];
    __syncthreads();
    unsigned short* B = (unsigned short*)ws;
    for (int idx = tid; idx < 4096; idx += 256) {
        const int s  = idx & 7;
        const int l  = (idx >> 3) & 63;
        const int h  = (idx >> 9) & 1;
        const int nt = idx >> 10;
        const int jp = 4 * (l & 15) + nt;
        const int kp = 32 * h + 8 * (l >> 4) + s;
        float v = 0.0f;
        if (jp < TS && kp < TS) {
            const int jj = (jp + 1) % TS, kk = (kp + 1) % TS;
            v = __expf(tr[jj * TS + kk] - Tmax);
        }
        unsigned bts = __float_as_uint(v);
        B[idx] = (unsigned short)((bts + 0x7FFFu + ((bts >> 16) & 1u)) >> 16);  // rne bf16
    }
    if (tid == 0) ((float*)ws)[2048] = Tmax;  // byte 8192
}

__device__ __forceinline__ unsigned cvtpk_bf16(float lo, float hi) {
    unsigned d;  // D[15:0]=bf16(lo), D[31:16]=bf16(hi)
    asm("v_cvt_pk_bf16_f32 %0, %1, %2" : "=v"(d) : "v"(lo), "v"(hi));
    return d;
}

// One wave = 4 chains: internal V-row = 4*(l>>4), global chain = b0 + (l>>4).
// Internal rows 4g+1..4g+3 are dead (zeroed once). Position p = 4*(l&15)+nt.
// V16: chain-major [16][64 bf16], XOR-swizzled (R8-validated, 0 bank conflicts).
__global__ __launch_bounds__(64, 2) void crf_fwd(const float* __restrict__ emis,
                                                 const unsigned short* __restrict__ wsB,
                                                 float* __restrict__ out, int L) {
    __shared__ __align__(16) unsigned short V16[1024];
    const int l = threadIdx.x, g = l >> 4, c0 = l & 15;
    const int b0 = blockIdx.x * 4;
    const float Tmax = ((const float*)wsB)[2048];

    // E fragments (B-operand), register-resident
    bf16x8 Bf[4][2];
    {
        const bf16x8* Bt = (const bf16x8*)wsB;
        #pragma unroll
        for (int nt = 0; nt < 4; ++nt)
            #pragma unroll
            for (int h = 0; h < 2; ++h) Bf[nt][h] = Bt[(nt * 2 + h) * 64 + l];
    }

    // V16 LDS indices (R8-validated swizzle)
    int wi[4];
    #pragma unroll
    for (int t = 0; t < 4; ++t) {
        const int ch = 4 * g + t;
        wi[t] = ch * 16 + (c0 ^ ((ch & 7) << 1));  // uint2 units
    }
    const int ra0 = c0 * 8 + (g ^ (c0 & 7));        // bf16x8 units, k 0..31
    const int ra1 = c0 * 8 + ((4 + g) ^ (c0 & 7));  // k 32..63
    uint2* const Vw = (uint2*)V16;
    const bf16x8* const Vr = (const bf16x8*)V16;

    // zero dead internal rows (t=1..3) once
    {
        const uint2 z = {0u, 0u};
        Vw[wi[1]] = z;
        Vw[wi[2]] = z;
        Vw[wi[3]] = z;
    }

    // Emission addressing: positions 4c0..4c0+3 (aligned x4); edge lanes clamp to 45.
    const int LT = L * TS;
    const bool sel12 = (c0 >= 12);
    const int col4 = sel12 ? 45 : 4 * c0;
    const float* const ebase = emis + (size_t)(b0 + g) * LT + col4;

    f32x4 pf[4];  // [slot], statically indexed only

#define LQ(STEP, SLOT) do {                                                           \
    pf[SLOT] = *(const f32x4u*)(ebase + (STEP) * TS);                                 \
} while (0)

#define EESEL(DST, SLOT) do {                                                         \
    const f32x4 q = pf[SLOT];                                                         \
    DST[0] = __expf(sel12 ? q.w : q.x);                                               \
    DST[1] = __expf(q.y);                                                             \
    DST[2] = __expf(q.z);                                                             \
    DST[3] = __expf(q.w);                                                             \
} while (0)

    // prologue: fill 4 slots
    LQ(0, 0);
    if (L > 1) LQ(1, 1);
    if (L > 2) LQ(2, 2);
    if (L > 3) LQ(3, 3);

    // init V_0 from slot 0: v = exp(emit[0][p]), dead positions -> 0
    float v[4];
    {
        const f32x4 q = pf[0];
        const float i0 = sel12 ? q.w : q.x;
        v[0] = (4 * c0 + 0 < TS) ? __expf(i0)  : 0.0f;
        v[1] = (4 * c0 + 1 < TS) ? __expf(q.y) : 0.0f;
        v[2] = (4 * c0 + 2 < TS) ? __expf(q.z) : 0.0f;
        v[3] = (4 * c0 + 3 < TS) ? __expf(q.w) : 0.0f;
    }

    float ee0[4], ee1[4];
    EESEL(ee1, 1);  // emissions for step 1

    float sc = 0.f, fac = 1.f, pend = 0.f;

#define STEP(I, EC, EN, SN, SL, DO_C, DO_A) do {                                      \
    /* 1: pack v -> bf16, 1 x ds_write_b64 (swizzled); row 4g */                      \
    {                                                                                 \
        uint2 u;                                                                      \
        u.x = cvtpk_bf16(v[0], v[1]);                                                 \
        u.y = cvtpk_bf16(v[2], v[3]);                                                 \
        Vw[wi[0]] = u;                                                                \
    }                                                                                 \
    /* 2: next step's ee (pads DS drain; loads landed >=2 steps ago) */               \
    EESEL(EN, SN);                                                                    \
    /* 3: issue loads for step I+3 into the freed slot */                             \
    if ((I) + 3 < L) LQ((I) + 3, SL);                                                 \
    asm volatile("" ::: "memory");                                                    \
    /* 4: A-fragments (conflict-free b128; same-wave DS in-order) */                  \
    const bf16x8 A0 = Vr[ra0];                                                        \
    const bf16x8 A1 = Vr[ra1];                                                        \
    /* 5+6: MFMA + emission/renorm multiply (C row t=0 live) */                       \
    _Pragma("unroll")                                                                 \
    for (int nt = 0; nt < 4; ++nt) {                                                  \
        f32x4 acc = {0.f, 0.f, 0.f, 0.f};                                             \
        acc = __builtin_amdgcn_mfma_f32_16x16x32_bf16(A0, Bf[nt][0], acc, 0, 0, 0);   \
        acc = __builtin_amdgcn_mfma_f32_16x16x32_bf16(A1, Bf[nt][1], acc, 0, 0, 0);   \
        float nv = acc[0] * EC[nt];                                                   \
        if (DO_A) nv *= fac;                                                          \
        v[nt] = nv;                                                                   \
    }                                                                                 \
    if (DO_A) sc += pend;                                                             \
    /* 7: renorm factor (applied next step; off critical path) */                     \
    if (DO_C) {                                                                       \
        float mx = fmaxf(fmaxf(v[0], v[1]), fmaxf(v[2], v[3]));                       \
        mx = fmaxf(mx, __shfl_xor(mx, 1, 64));                                        \
        mx = fmaxf(mx, __shfl_xor(mx, 2, 64));                                        \
        mx = fmaxf(mx, __shfl_xor(mx, 4, 64));                                        \
        mx = fmaxf(mx, __shfl_xor(mx, 8, 64));                                        \
        const unsigned ex = __float_as_uint(mx) >> 23;                                \
        fac  = __uint_as_float((254u - ex) << 23);                                    \
        pend = (float)((int)ex - 127) * LN2;                                          \
    }                                                                                 \
} while (0)

    const int S = L - 1;  // steps 1..S
    int i = 1;
    for (; i + 3 <= S; i += 4) {  // i == 1 mod 4 -> static pf slots
        STEP(i + 0, ee1, ee0, 2, 0, 1, 0);
        STEP(i + 1, ee0, ee1, 3, 1, 0, 1);
        STEP(i + 2, ee1, ee0, 0, 2, 0, 0);
        STEP(i + 3, ee0, ee1, 1, 3, 0, 0);
    }
    if (i <= S)     STEP(i,     ee1, ee0, 2, 0, 1, 0);
    if (i + 1 <= S) STEP(i + 1, ee0, ee1, 3, 1, 0, 1);
    if (i + 2 <= S) STEP(i + 2, ee1, ee0, 0, 2, 0, 0);
#undef STEP
#undef EESEL
#undef LQ

    // final: alpha[chain] = sc + log(sum_p V) + LOG49 + (L-1)*Tmax
    float s = (v[0] + v[1]) + (v[2] + v[3]);
    s += __shfl_xor(s, 1, 64);
    s += __shfl_xor(s, 2, 64);
    s += __shfl_xor(s, 4, 64);
    s += __shfl_xor(s, 8, 64);
    const float res = sc + __logf(s) + LOG49 + (float)(L - 1) * Tmax;
    if (c0 == 0) out[b0 + g] = res;
}

extern "C" void kernel_launch(void* const* d_in, const int* in_sizes, int n_in,
                              void* d_out, int out_size, void* d_ws, size_t ws_size,
                              hipStream_t stream) {
    const float* emis = (const float*)d_in[0];
    const float* tf   = (const float*)d_in[1];
    const float* w2   = (const float*)d_in[2];
    const float* b2   = (const float*)d_in[3];
    float* out = (float*)d_out;
    float* ws  = (float*)d_ws;

    const int B = out_size;                // 8192
    const int L = in_sizes[0] / (B * TS);  // 48

    prep_kernel<<<1, 256, 0, stream>>>(tf, w2, b2, ws);
    crf_fwd<<<B / 4, 64, 0, stream>>>(emis, (const unsigned short*)ws, out, L);
}